// Round 11
// baseline (366.855 us; speedup 1.0000x reference)
//
#include <hip/hip_runtime.h>
#include <hip/hip_fp16.h>

#define NN 50000
#define NNP 50048        // padded node count for table rows
#define EE 800000
#define CH 32            // count chunks (25000 edges each)
#define CHE (EE / CH)    // 25000
#define NB_E2 1563       // ceil(400000/256): 2 edges/thread grids (k_edge)
#define NWIN 4           // windows (XCD pairs): csr seg ~800KB fits per-XCD L2
#define WIN 12500        // node-window per slot (4 * 12500 = 50000)
#define EPB 1024         // edges per fill chunk (256 thr x 4)
#define NCHUNK 782       // ceil(800000/1024)

// ---------------- windowed LDS count: NO device atomics ----------------
__global__ __launch_bounds__(256) void k_count(
    const int* __restrict__ ei, unsigned* __restrict__ pk, int* __restrict__ part)
{
    __shared__ int hist[WIN];   // 50KB
    int c = blockIdx.x >> 2;
    int w = blockIdx.x & 3;
    int tid = threadIdx.x;
    for (int i = tid; i < WIN; i += 256) hist[i] = 0;
    __syncthreads();
    int e0 = c * CHE;
    unsigned lo = w * WIN;
    const int* cols = ei + EE + e0;
    for (int i = tid; i < CHE / 4; i += 256) {
        int4 cc = *(const int4*)(cols + i * 4);
        unsigned d;
        d = (unsigned)cc.x - lo;
        if (d < WIN) {
            int r = atomicAdd(&hist[d], 1);
            pk[e0 + i * 4 + 0] = (unsigned)cc.x | ((unsigned)c << 16) | ((unsigned)r << 21);
        }
        d = (unsigned)cc.y - lo;
        if (d < WIN) {
            int r = atomicAdd(&hist[d], 1);
            pk[e0 + i * 4 + 1] = (unsigned)cc.y | ((unsigned)c << 16) | ((unsigned)r << 21);
        }
        d = (unsigned)cc.z - lo;
        if (d < WIN) {
            int r = atomicAdd(&hist[d], 1);
            pk[e0 + i * 4 + 2] = (unsigned)cc.z | ((unsigned)c << 16) | ((unsigned)r << 21);
        }
        d = (unsigned)cc.w - lo;
        if (d < WIN) {
            int r = atomicAdd(&hist[d], 1);
            pk[e0 + i * 4 + 3] = (unsigned)cc.w | ((unsigned)c << 16) | ((unsigned)r << 21);
        }
    }
    __syncthreads();
    int* pc = part + (size_t)c * NNP + lo;
    for (int i = tid; i < WIN; i += 256) pc[i] = hist[i];
}

// ---------------- reduce partials -> cnt + dis ----------------
__global__ void k_reduce(const int* __restrict__ part, int* __restrict__ cnt,
                         float* __restrict__ dis) {
    int i = blockIdx.x * 256 + threadIdx.x;
    if (i >= NN) return;
    int v = 0;
#pragma unroll
    for (int c = 0; c < CH; c++) v += part[(size_t)c * NNP + i];
    cnt[i] = v;
    dis[i] = rsqrtf((float)v + 1.0f);  // +1 self loop
}

// ---------------- scan: starts + sd + per-chunk base table ----------------
__global__ void k_scan(const int* __restrict__ cnt, const int* __restrict__ part,
                       int2* __restrict__ sd, int* __restrict__ chunkstart, int n) {
    __shared__ int s[256];
    int tid = threadIdx.x, b = blockIdx.x;
    int i = b * 256 + tid;
    int v = (i < n) ? cnt[i] : 0;
    s[tid] = v;
    __syncthreads();
    for (int off = 1; off < 256; off <<= 1) {
        int t2 = (tid >= off) ? s[tid - off] : 0;
        __syncthreads();
        if (tid >= off) s[tid] += t2;
        __syncthreads();
    }
    int loc = s[tid] - v;   // block-local exclusive
    int lim = b * 256;
    int pre = 0;
    for (int j = tid * 4; j < lim; j += 1024) {
        int4 c4 = *(const int4*)(cnt + j);
        pre += c4.x + c4.y + c4.z + c4.w;
    }
    __syncthreads();
    s[tid] = pre;
    __syncthreads();
    for (int off = 128; off; off >>= 1) {
        if (tid < off) s[tid] += s[tid + off];
        __syncthreads();
    }
    int boff = s[0];
    if (i < n) {
        int st = loc + boff;
        sd[i] = make_int2(st, v);
        int cs = st;
#pragma unroll
        for (int c = 0; c < CH; c++) {
            chunkstart[(size_t)c * NNP + i] = cs;
            cs += part[(size_t)c * NNP + i];
        }
    }
}

// ---------------- CSR fill: atomic-free, windowed scatter, packed reads ----------------
__global__ __launch_bounds__(256) void k_fill(
    const int* __restrict__ ei, const unsigned* __restrict__ pk,
    const int* __restrict__ chunkstart, int* __restrict__ csr)
{
    int w = blockIdx.x & (NWIN - 1);
    int chunk = blockIdx.x >> 2;
    int base = chunk * EPB + threadIdx.x * 4;
    unsigned lo = w * WIN;
    if (base + 3 < EE) {
        int4 rr = *(const int4*)(ei + base);
        uint4 pp = *(const uint4*)(pk + base);
        unsigned c0 = pp.x & 0xffffu, c1 = pp.y & 0xffffu;
        unsigned c2 = pp.z & 0xffffu, c3 = pp.w & 0xffffu;
        if (c0 - lo < WIN) csr[chunkstart[(size_t)((pp.x >> 16) & 31u) * NNP + c0] + (pp.x >> 21)] = rr.x;
        if (c1 - lo < WIN) csr[chunkstart[(size_t)((pp.y >> 16) & 31u) * NNP + c1] + (pp.y >> 21)] = rr.y;
        if (c2 - lo < WIN) csr[chunkstart[(size_t)((pp.z >> 16) & 31u) * NNP + c2] + (pp.z >> 21)] = rr.z;
        if (c3 - lo < WIN) csr[chunkstart[(size_t)((pp.w >> 16) & 31u) * NNP + c3] + (pp.w >> 21)] = rr.w;
    } else {
        for (int e = 0; e < 4; e++) {
            int t = base + e;
            if (t < EE) {
                unsigned pv = pk[t];
                unsigned cgl = pv & 0xffffu;
                if (cgl - lo < WIN)
                    csr[chunkstart[(size_t)((pv >> 16) & 31u) * NNP + cgl] + (pv >> 21)] = ei[t];
            }
        }
    }
}

// ---------------- GEMM: LDS-staged x, 2-way K-SPLIT for occupancy ----------------
// r10 lesson: output-split halved per-wave FMA:s_load ratio -> W scalar latency
// exposed. K-split keeps acc[32] (32 FMA per k, W latency covered) while doubling
// waves: 256 thr = 128 rows x 2 k-halves; each half accumulates 64 of 128 k;
// halves summed via reused LDS. Grid 391x3, LDS 33KB -> 4 blk/CU = 16 waves/CU
// (was 9.2). Only 2 staging barriers (was 4). Reorder: (k0-31,64-95)+(k32-63,
// 96-127) per output — benign fp32 reassociation.
__global__ __launch_bounds__(256) void k_gemm(
    const float* __restrict__ x, const float* __restrict__ Wb,
    const float* __restrict__ Wc, const float* __restrict__ bc,
    const float* __restrict__ dis,
    __half* __restrict__ bsh, float* __restrict__ wcomb, int n)
{
    __shared__ float xt[64 * 129];  // [local k][row], 33KB; reused for combine
    int tid = threadIdx.x;
    int grp = blockIdx.y;
    int row0 = blockIdx.x * 128;
    int rloc = tid & 127;
    int kh = tid >> 7;              // k-half (wave-uniform: waves 0,1 -> 0; 2,3 -> 1)
    int row = row0 + rloc;
    bool valid = row < n;

    const float* W = (grp < 2) ? (Wb + grp * 32) : Wc;
    const int ldw = (grp < 2) ? 64 : 32;

    float acc[32];
#pragma unroll
    for (int c = 0; c < 32; c++) acc[c] = 0.f;

    for (int s = 0; s < 2; s++) {
        int base_k = s * 64;
        float4 v[8];
#pragma unroll
        for (int i = 0; i < 8; i++) {
            int idx = i * 256 + tid;    // 0..2047: 128 rows x 16 float4
            int r = idx >> 4;
            int k4 = idx & 15;
            int gr = row0 + r;
            v[i] = (gr < n) ? *(const float4*)(x + (size_t)gr * 128 + base_k + k4 * 4)
                            : make_float4(0.f, 0.f, 0.f, 0.f);
        }
        __syncthreads();
#pragma unroll
        for (int i = 0; i < 8; i++) {
            int idx = i * 256 + tid;
            int r = idx >> 4;
            int k4 = idx & 15;
            xt[(k4 * 4 + 0) * 129 + r] = v[i].x;
            xt[(k4 * 4 + 1) * 129 + r] = v[i].y;
            xt[(k4 * 4 + 2) * 129 + r] = v[i].z;
            xt[(k4 * 4 + 3) * 129 + r] = v[i].w;
        }
        __syncthreads();

        const float* Ws = W + (base_k + kh * 32) * ldw;
#pragma unroll 8
        for (int k = 0; k < 32; k++) {
            float xs = xt[(kh * 32 + k) * 129 + rloc];
            const float* wk = Ws + k * ldw;
#pragma unroll
            for (int c = 0; c < 32; c++) acc[c] = fmaf(xs, wk[c], acc[c]);
        }
    }

    // combine k-halves through reused LDS: [128][33] floats (16.9KB < 33KB)
    __syncthreads();                 // all xt FMA reads complete
    if (kh) {
#pragma unroll
        for (int c = 0; c < 32; c++) xt[rloc * 33 + c] = acc[c];
    }
    __syncthreads();
    if (kh) return;
#pragma unroll
    for (int c = 0; c < 32; c++) acc[c] += xt[rloc * 33 + c];

    if (!valid) return;
    if (grp < 2) {
        float d = dis[row];
        __half2 hh[16];
#pragma unroll
        for (int c = 0; c < 16; c++)
            hh[c] = __floats2half2_rn(acc[2 * c] * d, acc[2 * c + 1] * d);
        uint4* bo = (uint4*)(bsh + (size_t)row * 64 + grp * 32);
        const uint4* src = (const uint4*)hh;
#pragma unroll
        for (int c = 0; c < 4; c++) bo[c] = src[c];
    } else {
        float4* wo = (float4*)(wcomb + (size_t)row * 32);
#pragma unroll
        for (int c = 0; c < 8; c++)
            wo[c] = make_float4(acc[4*c] + bc[4*c], acc[4*c+1] + bc[4*c+1],
                                acc[4*c+2] + bc[4*c+2], acc[4*c+3] + bc[4*c+3]);
    }
}

// ---------------- fused aggregate (fp16 gather, pipelined, 8 edges/iter) + combine ----------------
template<int LAYER2>
__global__ __launch_bounds__(256) void k_agg(
    const int* __restrict__ csr, const int2* __restrict__ sd,
    const __half* __restrict__ bsh, const float* __restrict__ dis,
    const float* __restrict__ wcomb, const float* __restrict__ bias,
    float* __restrict__ h,
    const float* __restrict__ Wcls, const float* __restrict__ bcls,
    float* __restrict__ p, int n)
{
    int wid = (blockIdx.x * 256 + threadIdx.x) >> 6;
    int lane = threadIdx.x & 63;
    if (wid >= n) return;
    int2 s2 = sd[wid];
    int start = s2.x, deg = s2.y;
    int g = lane >> 4, q = lane & 15;

    const uint2* bsp = (const uint2*)bsh;
    float4 acc4 = make_float4(0.f, 0.f, 0.f, 0.f);
    if (g == 0) {  // self-loop term (pre-scaled)
        uint2 v = bsp[(size_t)wid * 16 + q];
        float2 lo = __half22float2(*(const __half2*)&v.x);
        float2 hi = __half22float2(*(const __half2*)&v.y);
        acc4 = make_float4(lo.x, lo.y, hi.x, hi.y);
    }

    int j = 0;
    int ia = 0, ib = 0;
    if (8 <= deg) { ia = csr[start + g]; ib = csr[start + 4 + g]; }
    while (j + 8 <= deg) {
        int jn = j + 8;
        int na = 0, nb = 0;
        if (jn + 8 <= deg) { na = csr[start + jn + g]; nb = csr[start + jn + 4 + g]; }
        uint2 v0 = bsp[(size_t)ia * 16 + q];
        uint2 v1 = bsp[(size_t)ib * 16 + q];
        float2 l0 = __half22float2(*(const __half2*)&v0.x);
        float2 h0 = __half22float2(*(const __half2*)&v0.y);
        float2 l1 = __half22float2(*(const __half2*)&v1.x);
        float2 h1 = __half22float2(*(const __half2*)&v1.y);
        acc4.x += l0.x + l1.x;
        acc4.y += l0.y + l1.y;
        acc4.z += h0.x + h1.x;
        acc4.w += h0.y + h1.y;
        ia = na; ib = nb; j = jn;
    }
    int last = start + deg - 1;
    for (; j < deg; j += 4) {
        int idx = start + j + g;
        int r = csr[min(idx, last)];
        uint2 v = bsp[(size_t)r * 16 + q];
        float2 lo = __half22float2(*(const __half2*)&v.x);
        float2 hi = __half22float2(*(const __half2*)&v.y);
        float m = (j + g < deg) ? 1.f : 0.f;
        acc4.x = fmaf(lo.x, m, acc4.x);
        acc4.y = fmaf(lo.y, m, acc4.y);
        acc4.z = fmaf(hi.x, m, acc4.z);
        acc4.w = fmaf(hi.y, m, acc4.w);
    }

    acc4.x += __shfl_xor(acc4.x, 16, 64);
    acc4.y += __shfl_xor(acc4.y, 16, 64);
    acc4.z += __shfl_xor(acc4.z, 16, 64);
    acc4.w += __shfl_xor(acc4.w, 16, 64);
    acc4.x += __shfl_xor(acc4.x, 32, 64);
    acc4.y += __shfl_xor(acc4.y, 32, 64);
    acc4.z += __shfl_xor(acc4.z, 32, 64);
    acc4.w += __shfl_xor(acc4.w, 32, 64);

    float d = dis[wid];
    acc4.x *= d; acc4.y *= d; acc4.z *= d; acc4.w *= d;

    int src = lane >> 2;
    float t0 = __shfl(acc4.x, src, 64);
    float t1 = __shfl(acc4.y, src, 64);
    float t2 = __shfl(acc4.z, src, 64);
    float t3 = __shfl(acc4.w, src, 64);
    int c = lane & 3;
    float acc = (c == 0) ? t0 : (c == 1) ? t1 : (c == 2) ? t2 : t3;

    int fh = lane & 15;
    float a0 = __shfl(acc, fh, 64);
    float a1 = __shfl(acc, 16 + fh, 64);
    float a2 = __shfl(acc, 32 + fh, 64);
    float a3 = __shfl(acc, 48 + fh, 64);
    const float* wn = wcomb + (size_t)wid * 32;
    int hd = lane >> 4;
    float s1 = bias[lane];
    float s2v = bias[64 + lane];
    s1 = fmaf(wn[hd * 4 + 0], a0, s1);
    s1 = fmaf(wn[hd * 4 + 1], a1, s1);
    s1 = fmaf(wn[hd * 4 + 2], a2, s1);
    s1 = fmaf(wn[hd * 4 + 3], a3, s1);
    s2v = fmaf(wn[(4 + hd) * 4 + 0], a0, s2v);
    s2v = fmaf(wn[(4 + hd) * 4 + 1], a1, s2v);
    s2v = fmaf(wn[(4 + hd) * 4 + 2], a2, s2v);
    s2v = fmaf(wn[(4 + hd) * 4 + 3], a3, s2v);

    if (!LAYER2) {
        s1 = fmaxf(s1, 0.f);
        s2v = fmaxf(s2v, 0.f);
        h[(size_t)wid * 128 + lane] = s1;
        h[(size_t)wid * 128 + 64 + lane] = s2v;
    } else {
        float r0 = s1 * Wcls[lane * 2 + 0] + s2v * Wcls[(64 + lane) * 2 + 0];
        float r1 = s1 * Wcls[lane * 2 + 1] + s2v * Wcls[(64 + lane) * 2 + 1];
        float r2 = s1 * Wcls[(128 + lane) * 2 + 0] + s2v * Wcls[(192 + lane) * 2 + 0];
        float r3 = s1 * Wcls[(128 + lane) * 2 + 1] + s2v * Wcls[(192 + lane) * 2 + 1];
#pragma unroll
        for (int off = 32; off; off >>= 1) {
            r0 += __shfl_xor(r0, off, 64);
            r1 += __shfl_xor(r1, off, 64);
            r2 += __shfl_xor(r2, off, 64);
            r3 += __shfl_xor(r3, off, 64);
        }
        if (lane == 0) {
            p[wid * 4 + 0] = r0 + bcls[0];
            p[wid * 4 + 1] = r1 + bcls[1];
            p[wid * 4 + 2] = r2;
            p[wid * 4 + 3] = r3;
        }
    }
}

// ---------------- edge output: 2 edges/thread ----------------
__global__ void k_edge(const int* __restrict__ ei, const float* __restrict__ p,
                       float* __restrict__ out)
{
    int t = blockIdx.x * blockDim.x + threadIdx.x;
    if (t >= EE / 2) return;
    int2 rr = *(const int2*)(ei + 2 * t);
    int2 cc = *(const int2*)(ei + EE + 2 * t);
    float2 pt0 = *(const float2*)(p + rr.x * 4);
    float2 pt1 = *(const float2*)(p + rr.y * 4);
    float2 pb0 = *(const float2*)(p + cc.x * 4 + 2);
    float2 pb1 = *(const float2*)(p + cc.y * 4 + 2);
    float4 o;
    o.x = pt0.x + pb0.x;
    o.y = pt0.y + pb0.y;
    o.z = pt1.x + pb1.x;
    o.w = pt1.y + pb1.y;
    *(float4*)(out + (size_t)t * 4) = o;
}

extern "C" void kernel_launch(void* const* d_in, const int* in_sizes, int n_in,
                              void* d_out, int out_size, void* d_ws, size_t ws_size,
                              hipStream_t stream) {
    const float* x    = (const float*)d_in[0];
    const int*   ei   = (const int*)d_in[1];
    const float* Wb1  = (const float*)d_in[2];
    const float* Wc1  = (const float*)d_in[3];
    const float* bc1  = (const float*)d_in[4];
    const float* b1   = (const float*)d_in[5];
    const float* Wb2  = (const float*)d_in[6];
    const float* Wc2  = (const float*)d_in[7];
    const float* bc2  = (const float*)d_in[8];
    const float* b2   = (const float*)d_in[9];
    const float* Wcls = (const float*)d_in[10];
    const float* bcls = (const float*)d_in[11];
    float* out = (float*)d_out;

    char* ws = (char*)d_ws;
    size_t off = 0;
    auto alloc = [&](size_t bytes) {
        void* pp = ws + off;
        off += (bytes + 15) & ~(size_t)15;
        return pp;
    };

    float*    dis    = (float*)alloc(50048 * 4);
    __half*   bsh    = (__half*)alloc((size_t)NN * 64 * 2);
    float*    wcomb  = (float*)alloc((size_t)NN * 32 * 4);
    float*    h      = (float*)alloc((size_t)NN * 128 * 4);
    float*    p      = (float*)alloc((size_t)NN * 4 * 4);
    int*      cnt    = (int*)alloc(50048 * 4);
    int2*     sd     = (int2*)alloc((size_t)50048 * 8);
    int*      csr    = (int*)alloc((size_t)EE * 4);
    unsigned* pk     = (unsigned*)alloc((size_t)EE * 4);
    int*      part   = (int*)alloc((size_t)CH * NNP * 4);       // 6.4 MB
    int*      chunkstart = (int*)alloc((size_t)CH * NNP * 4);   // 6.4 MB

    const int B = 256;
    int gN   = (NN + B - 1) / B;   // 196
    int gN2  = (NN + 127) / 128;   // 391 row-blocks for k-split gemm
    int gN64 = (NN * 64) / B;      // 12500
    dim3 gG(gN2, 3);

    // CSR build (shared by both layers) — no memset, no device atomics
    k_count<<<CH * NWIN, B, 0, stream>>>(ei, pk, part);
    k_reduce<<<gN, B, 0, stream>>>(part, cnt, dis);
    k_scan<<<gN, B, 0, stream>>>(cnt, part, sd, chunkstart, NN);
    k_fill<<<NCHUNK * NWIN, B, 0, stream>>>(ei, pk, chunkstart, csr);

    // conv1
    k_gemm<<<gG, B, 0, stream>>>(x, Wb1, Wc1, bc1, dis, bsh, wcomb, NN);
    k_agg<0><<<gN64, B, 0, stream>>>(csr, sd, bsh, dis, wcomb, b1, h,
                                     Wcls, bcls, p, NN);

    // conv2 (+ fused edge-cls projection)
    k_gemm<<<gG, B, 0, stream>>>(h, Wb2, Wc2, bc2, dis, bsh, wcomb, NN);
    k_agg<1><<<gN64, B, 0, stream>>>(csr, sd, bsh, dis, wcomb, b2, h,
                                     Wcls, bcls, p, NN);

    // edge output
    k_edge<<<NB_E2, B, 0, stream>>>(ei, p, out);
}

// Round 12
// 335.033 us; speedup vs baseline: 1.0950x; 1.0950x over previous
//
#include <hip/hip_runtime.h>
#include <hip/hip_fp16.h>

#define NN 50000
#define NNP 50048        // padded node count for table rows
#define EE 800000
#define CH 32            // count chunks (25000 edges each)
#define CHE (EE / CH)    // 25000
#define NB_E2 1563       // ceil(400000/256): 2 edges/thread grids (k_edge)
#define NWIN 4           // windows (XCD pairs): csr seg ~800KB fits per-XCD L2
#define WIN 12500        // node-window per slot (4 * 12500 = 50000)
#define EPB 1024         // edges per fill chunk (256 thr x 4)
#define NCHUNK 782       // ceil(800000/1024)

// ---------------- windowed LDS count: NO device atomics ----------------
__global__ __launch_bounds__(256) void k_count(
    const int* __restrict__ ei, unsigned* __restrict__ pk, int* __restrict__ part)
{
    __shared__ int hist[WIN];   // 50KB
    int c = blockIdx.x >> 2;
    int w = blockIdx.x & 3;
    int tid = threadIdx.x;
    for (int i = tid; i < WIN; i += 256) hist[i] = 0;
    __syncthreads();
    int e0 = c * CHE;
    unsigned lo = w * WIN;
    const int* cols = ei + EE + e0;
    for (int i = tid; i < CHE / 4; i += 256) {
        int4 cc = *(const int4*)(cols + i * 4);
        unsigned d;
        d = (unsigned)cc.x - lo;
        if (d < WIN) {
            int r = atomicAdd(&hist[d], 1);
            pk[e0 + i * 4 + 0] = (unsigned)cc.x | ((unsigned)c << 16) | ((unsigned)r << 21);
        }
        d = (unsigned)cc.y - lo;
        if (d < WIN) {
            int r = atomicAdd(&hist[d], 1);
            pk[e0 + i * 4 + 1] = (unsigned)cc.y | ((unsigned)c << 16) | ((unsigned)r << 21);
        }
        d = (unsigned)cc.z - lo;
        if (d < WIN) {
            int r = atomicAdd(&hist[d], 1);
            pk[e0 + i * 4 + 2] = (unsigned)cc.z | ((unsigned)c << 16) | ((unsigned)r << 21);
        }
        d = (unsigned)cc.w - lo;
        if (d < WIN) {
            int r = atomicAdd(&hist[d], 1);
            pk[e0 + i * 4 + 3] = (unsigned)cc.w | ((unsigned)c << 16) | ((unsigned)r << 21);
        }
    }
    __syncthreads();
    int* pc = part + (size_t)c * NNP + lo;
    for (int i = tid; i < WIN; i += 256) pc[i] = hist[i];
}

// ---------------- reduce partials -> cnt + dis ----------------
__global__ void k_reduce(const int* __restrict__ part, int* __restrict__ cnt,
                         float* __restrict__ dis) {
    int i = blockIdx.x * 256 + threadIdx.x;
    if (i >= NN) return;
    int v = 0;
#pragma unroll
    for (int c = 0; c < CH; c++) v += part[(size_t)c * NNP + i];
    cnt[i] = v;
    dis[i] = rsqrtf((float)v + 1.0f);  // +1 self loop
}

// ---------------- scan: starts + sd + per-chunk base table ----------------
__global__ void k_scan(const int* __restrict__ cnt, const int* __restrict__ part,
                       int2* __restrict__ sd, int* __restrict__ chunkstart, int n) {
    __shared__ int s[256];
    int tid = threadIdx.x, b = blockIdx.x;
    int i = b * 256 + tid;
    int v = (i < n) ? cnt[i] : 0;
    s[tid] = v;
    __syncthreads();
    for (int off = 1; off < 256; off <<= 1) {
        int t2 = (tid >= off) ? s[tid - off] : 0;
        __syncthreads();
        if (tid >= off) s[tid] += t2;
        __syncthreads();
    }
    int loc = s[tid] - v;   // block-local exclusive
    int lim = b * 256;
    int pre = 0;
    for (int j = tid * 4; j < lim; j += 1024) {
        int4 c4 = *(const int4*)(cnt + j);
        pre += c4.x + c4.y + c4.z + c4.w;
    }
    __syncthreads();
    s[tid] = pre;
    __syncthreads();
    for (int off = 128; off; off >>= 1) {
        if (tid < off) s[tid] += s[tid + off];
        __syncthreads();
    }
    int boff = s[0];
    if (i < n) {
        int st = loc + boff;
        sd[i] = make_int2(st, v);
        int cs = st;
#pragma unroll
        for (int c = 0; c < CH; c++) {
            chunkstart[(size_t)c * NNP + i] = cs;
            cs += part[(size_t)c * NNP + i];
        }
    }
}

// ---------------- CSR fill: atomic-free, windowed scatter, packed reads ----------------
__global__ __launch_bounds__(256) void k_fill(
    const int* __restrict__ ei, const unsigned* __restrict__ pk,
    const int* __restrict__ chunkstart, int* __restrict__ csr)
{
    int w = blockIdx.x & (NWIN - 1);
    int chunk = blockIdx.x >> 2;
    int base = chunk * EPB + threadIdx.x * 4;
    unsigned lo = w * WIN;
    if (base + 3 < EE) {
        int4 rr = *(const int4*)(ei + base);
        uint4 pp = *(const uint4*)(pk + base);
        unsigned c0 = pp.x & 0xffffu, c1 = pp.y & 0xffffu;
        unsigned c2 = pp.z & 0xffffu, c3 = pp.w & 0xffffu;
        if (c0 - lo < WIN) csr[chunkstart[(size_t)((pp.x >> 16) & 31u) * NNP + c0] + (pp.x >> 21)] = rr.x;
        if (c1 - lo < WIN) csr[chunkstart[(size_t)((pp.y >> 16) & 31u) * NNP + c1] + (pp.y >> 21)] = rr.y;
        if (c2 - lo < WIN) csr[chunkstart[(size_t)((pp.z >> 16) & 31u) * NNP + c2] + (pp.z >> 21)] = rr.z;
        if (c3 - lo < WIN) csr[chunkstart[(size_t)((pp.w >> 16) & 31u) * NNP + c3] + (pp.w >> 21)] = rr.w;
    } else {
        for (int e = 0; e < 4; e++) {
            int t = base + e;
            if (t < EE) {
                unsigned pv = pk[t];
                unsigned cgl = pv & 0xffffu;
                if (cgl - lo < WIN)
                    csr[chunkstart[(size_t)((pv >> 16) & 31u) * NNP + cgl] + (pv >> 21)] = ei[t];
            }
        }
    }
}

// ---------------- GEMM: 3 grps FUSED into one block (x-tile staged ONCE) ----------------
// r10/r11 lesson: smaller row tiles buy occupancy but lose x's cross-grp L2 reuse
// (FETCH 25.6->38MB) — net loss. Instead fuse the 3 grp dispatch-columns into one
// block: stage x tile once (was 3x), 96 FMA/k (was 32) so W s_load latency is
// covered 3x better, barrier drains per row-tile drop 12->4. Grid 196, FETCH
// unchanged. FMA order per output bit-identical to r8 (grp loop reorders only
// across independent outputs).
__global__ __launch_bounds__(256) void k_gemm(
    const float* __restrict__ x, const float* __restrict__ Wb,
    const float* __restrict__ Wc, const float* __restrict__ bc,
    const float* __restrict__ dis,
    __half* __restrict__ bsh, float* __restrict__ wcomb, int n)
{
    __shared__ float xt[32 * 257];  // transposed tile: xt[k][row]
    int tid = threadIdx.x;
    int row0 = blockIdx.x * 256;
    int row = row0 + tid;
    bool valid = row < n;

    float acc0[32], acc1[32], acc2[32];
#pragma unroll
    for (int c = 0; c < 32; c++) { acc0[c] = 0.f; acc1[c] = 0.f; acc2[c] = 0.f; }

    for (int s = 0; s < 4; s++) {
        int base_k = s * 32;
        float4 v[8];
#pragma unroll
        for (int i = 0; i < 8; i++) {
            int idx = i * 256 + tid;
            int r = idx >> 3;
            int k4 = idx & 7;
            int gr = row0 + r;
            v[i] = (gr < n) ? *(const float4*)(x + (size_t)gr * 128 + base_k + k4 * 4)
                            : make_float4(0.f, 0.f, 0.f, 0.f);
        }
        __syncthreads();
#pragma unroll
        for (int i = 0; i < 8; i++) {
            int idx = i * 256 + tid;
            int r = idx >> 3;
            int k4 = idx & 7;
            xt[(k4 * 4 + 0) * 257 + r] = v[i].x;
            xt[(k4 * 4 + 1) * 257 + r] = v[i].y;
            xt[(k4 * 4 + 2) * 257 + r] = v[i].z;
            xt[(k4 * 4 + 3) * 257 + r] = v[i].w;
        }
        __syncthreads();

        const float* Ws0 = Wb + base_k * 64;        // grp0: Wb cols 0..31
        const float* Ws1 = Wb + 32 + base_k * 64;   // grp1: Wb cols 32..63
        const float* Ws2 = Wc + base_k * 32;        // grp2: Wc
#pragma unroll 4
        for (int k = 0; k < 32; k++) {
            float xs = xt[k * 257 + tid];
            const float* w0 = Ws0 + k * 64;
            const float* w1 = Ws1 + k * 64;
            const float* w2 = Ws2 + k * 32;
#pragma unroll
            for (int c = 0; c < 32; c++) acc0[c] = fmaf(xs, w0[c], acc0[c]);
#pragma unroll
            for (int c = 0; c < 32; c++) acc1[c] = fmaf(xs, w1[c], acc1[c]);
#pragma unroll
            for (int c = 0; c < 32; c++) acc2[c] = fmaf(xs, w2[c], acc2[c]);
        }
    }

    if (!valid) return;
    float d = dis[row];
    __half2 hh[16];
#pragma unroll
    for (int c = 0; c < 16; c++)
        hh[c] = __floats2half2_rn(acc0[2 * c] * d, acc0[2 * c + 1] * d);
    {
        uint4* bo = (uint4*)(bsh + (size_t)row * 64);
        const uint4* src = (const uint4*)hh;
#pragma unroll
        for (int c = 0; c < 4; c++) bo[c] = src[c];
    }
#pragma unroll
    for (int c = 0; c < 16; c++)
        hh[c] = __floats2half2_rn(acc1[2 * c] * d, acc1[2 * c + 1] * d);
    {
        uint4* bo = (uint4*)(bsh + (size_t)row * 64 + 32);
        const uint4* src = (const uint4*)hh;
#pragma unroll
        for (int c = 0; c < 4; c++) bo[c] = src[c];
    }
    float4* wo = (float4*)(wcomb + (size_t)row * 32);
#pragma unroll
    for (int c = 0; c < 8; c++)
        wo[c] = make_float4(acc2[4*c] + bc[4*c], acc2[4*c+1] + bc[4*c+1],
                            acc2[4*c+2] + bc[4*c+2], acc2[4*c+3] + bc[4*c+3]);
}

// ---------------- fused aggregate (fp16 gather, pipelined, 8 edges/iter) + combine ----------------
template<int LAYER2>
__global__ __launch_bounds__(256) void k_agg(
    const int* __restrict__ csr, const int2* __restrict__ sd,
    const __half* __restrict__ bsh, const float* __restrict__ dis,
    const float* __restrict__ wcomb, const float* __restrict__ bias,
    float* __restrict__ h,
    const float* __restrict__ Wcls, const float* __restrict__ bcls,
    float* __restrict__ p, int n)
{
    int wid = (blockIdx.x * 256 + threadIdx.x) >> 6;
    int lane = threadIdx.x & 63;
    if (wid >= n) return;
    int2 s2 = sd[wid];
    int start = s2.x, deg = s2.y;
    int g = lane >> 4, q = lane & 15;

    const uint2* bsp = (const uint2*)bsh;
    float4 acc4 = make_float4(0.f, 0.f, 0.f, 0.f);
    if (g == 0) {  // self-loop term (pre-scaled)
        uint2 v = bsp[(size_t)wid * 16 + q];
        float2 lo = __half22float2(*(const __half2*)&v.x);
        float2 hi = __half22float2(*(const __half2*)&v.y);
        acc4 = make_float4(lo.x, lo.y, hi.x, hi.y);
    }

    int j = 0;
    int ia = 0, ib = 0;
    if (8 <= deg) { ia = csr[start + g]; ib = csr[start + 4 + g]; }
    while (j + 8 <= deg) {
        int jn = j + 8;
        int na = 0, nb = 0;
        if (jn + 8 <= deg) { na = csr[start + jn + g]; nb = csr[start + jn + 4 + g]; }
        uint2 v0 = bsp[(size_t)ia * 16 + q];
        uint2 v1 = bsp[(size_t)ib * 16 + q];
        float2 l0 = __half22float2(*(const __half2*)&v0.x);
        float2 h0 = __half22float2(*(const __half2*)&v0.y);
        float2 l1 = __half22float2(*(const __half2*)&v1.x);
        float2 h1 = __half22float2(*(const __half2*)&v1.y);
        acc4.x += l0.x + l1.x;
        acc4.y += l0.y + l1.y;
        acc4.z += h0.x + h1.x;
        acc4.w += h0.y + h1.y;
        ia = na; ib = nb; j = jn;
    }
    int last = start + deg - 1;
    for (; j < deg; j += 4) {
        int idx = start + j + g;
        int r = csr[min(idx, last)];
        uint2 v = bsp[(size_t)r * 16 + q];
        float2 lo = __half22float2(*(const __half2*)&v.x);
        float2 hi = __half22float2(*(const __half2*)&v.y);
        float m = (j + g < deg) ? 1.f : 0.f;
        acc4.x = fmaf(lo.x, m, acc4.x);
        acc4.y = fmaf(lo.y, m, acc4.y);
        acc4.z = fmaf(hi.x, m, acc4.z);
        acc4.w = fmaf(hi.y, m, acc4.w);
    }

    acc4.x += __shfl_xor(acc4.x, 16, 64);
    acc4.y += __shfl_xor(acc4.y, 16, 64);
    acc4.z += __shfl_xor(acc4.z, 16, 64);
    acc4.w += __shfl_xor(acc4.w, 16, 64);
    acc4.x += __shfl_xor(acc4.x, 32, 64);
    acc4.y += __shfl_xor(acc4.y, 32, 64);
    acc4.z += __shfl_xor(acc4.z, 32, 64);
    acc4.w += __shfl_xor(acc4.w, 32, 64);

    float d = dis[wid];
    acc4.x *= d; acc4.y *= d; acc4.z *= d; acc4.w *= d;

    int src = lane >> 2;
    float t0 = __shfl(acc4.x, src, 64);
    float t1 = __shfl(acc4.y, src, 64);
    float t2 = __shfl(acc4.z, src, 64);
    float t3 = __shfl(acc4.w, src, 64);
    int c = lane & 3;
    float acc = (c == 0) ? t0 : (c == 1) ? t1 : (c == 2) ? t2 : t3;

    int fh = lane & 15;
    float a0 = __shfl(acc, fh, 64);
    float a1 = __shfl(acc, 16 + fh, 64);
    float a2 = __shfl(acc, 32 + fh, 64);
    float a3 = __shfl(acc, 48 + fh, 64);
    const float* wn = wcomb + (size_t)wid * 32;
    int hd = lane >> 4;
    float s1 = bias[lane];
    float s2v = bias[64 + lane];
    s1 = fmaf(wn[hd * 4 + 0], a0, s1);
    s1 = fmaf(wn[hd * 4 + 1], a1, s1);
    s1 = fmaf(wn[hd * 4 + 2], a2, s1);
    s1 = fmaf(wn[hd * 4 + 3], a3, s1);
    s2v = fmaf(wn[(4 + hd) * 4 + 0], a0, s2v);
    s2v = fmaf(wn[(4 + hd) * 4 + 1], a1, s2v);
    s2v = fmaf(wn[(4 + hd) * 4 + 2], a2, s2v);
    s2v = fmaf(wn[(4 + hd) * 4 + 3], a3, s2v);

    if (!LAYER2) {
        s1 = fmaxf(s1, 0.f);
        s2v = fmaxf(s2v, 0.f);
        h[(size_t)wid * 128 + lane] = s1;
        h[(size_t)wid * 128 + 64 + lane] = s2v;
    } else {
        float r0 = s1 * Wcls[lane * 2 + 0] + s2v * Wcls[(64 + lane) * 2 + 0];
        float r1 = s1 * Wcls[lane * 2 + 1] + s2v * Wcls[(64 + lane) * 2 + 1];
        float r2 = s1 * Wcls[(128 + lane) * 2 + 0] + s2v * Wcls[(192 + lane) * 2 + 0];
        float r3 = s1 * Wcls[(128 + lane) * 2 + 1] + s2v * Wcls[(192 + lane) * 2 + 1];
#pragma unroll
        for (int off = 32; off; off >>= 1) {
            r0 += __shfl_xor(r0, off, 64);
            r1 += __shfl_xor(r1, off, 64);
            r2 += __shfl_xor(r2, off, 64);
            r3 += __shfl_xor(r3, off, 64);
        }
        if (lane == 0) {
            p[wid * 4 + 0] = r0 + bcls[0];
            p[wid * 4 + 1] = r1 + bcls[1];
            p[wid * 4 + 2] = r2;
            p[wid * 4 + 3] = r3;
        }
    }
}

// ---------------- edge output: 2 edges/thread ----------------
__global__ void k_edge(const int* __restrict__ ei, const float* __restrict__ p,
                       float* __restrict__ out)
{
    int t = blockIdx.x * blockDim.x + threadIdx.x;
    if (t >= EE / 2) return;
    int2 rr = *(const int2*)(ei + 2 * t);
    int2 cc = *(const int2*)(ei + EE + 2 * t);
    float2 pt0 = *(const float2*)(p + rr.x * 4);
    float2 pt1 = *(const float2*)(p + rr.y * 4);
    float2 pb0 = *(const float2*)(p + cc.x * 4 + 2);
    float2 pb1 = *(const float2*)(p + cc.y * 4 + 2);
    float4 o;
    o.x = pt0.x + pb0.x;
    o.y = pt0.y + pb0.y;
    o.z = pt1.x + pb1.x;
    o.w = pt1.y + pb1.y;
    *(float4*)(out + (size_t)t * 4) = o;
}

extern "C" void kernel_launch(void* const* d_in, const int* in_sizes, int n_in,
                              void* d_out, int out_size, void* d_ws, size_t ws_size,
                              hipStream_t stream) {
    const float* x    = (const float*)d_in[0];
    const int*   ei   = (const int*)d_in[1];
    const float* Wb1  = (const float*)d_in[2];
    const float* Wc1  = (const float*)d_in[3];
    const float* bc1  = (const float*)d_in[4];
    const float* b1   = (const float*)d_in[5];
    const float* Wb2  = (const float*)d_in[6];
    const float* Wc2  = (const float*)d_in[7];
    const float* bc2  = (const float*)d_in[8];
    const float* b2   = (const float*)d_in[9];
    const float* Wcls = (const float*)d_in[10];
    const float* bcls = (const float*)d_in[11];
    float* out = (float*)d_out;

    char* ws = (char*)d_ws;
    size_t off = 0;
    auto alloc = [&](size_t bytes) {
        void* pp = ws + off;
        off += (bytes + 15) & ~(size_t)15;
        return pp;
    };

    float*    dis    = (float*)alloc(50048 * 4);
    __half*   bsh    = (__half*)alloc((size_t)NN * 64 * 2);
    float*    wcomb  = (float*)alloc((size_t)NN * 32 * 4);
    float*    h      = (float*)alloc((size_t)NN * 128 * 4);
    float*    p      = (float*)alloc((size_t)NN * 4 * 4);
    int*      cnt    = (int*)alloc(50048 * 4);
    int2*     sd     = (int2*)alloc((size_t)50048 * 8);
    int*      csr    = (int*)alloc((size_t)EE * 4);
    unsigned* pk     = (unsigned*)alloc((size_t)EE * 4);
    int*      part   = (int*)alloc((size_t)CH * NNP * 4);       // 6.4 MB
    int*      chunkstart = (int*)alloc((size_t)CH * NNP * 4);   // 6.4 MB

    const int B = 256;
    int gN   = (NN + B - 1) / B;   // 196
    int gN64 = (NN * 64) / B;      // 12500

    // CSR build (shared by both layers) — no memset, no device atomics
    k_count<<<CH * NWIN, B, 0, stream>>>(ei, pk, part);
    k_reduce<<<gN, B, 0, stream>>>(part, cnt, dis);
    k_scan<<<gN, B, 0, stream>>>(cnt, part, sd, chunkstart, NN);
    k_fill<<<NCHUNK * NWIN, B, 0, stream>>>(ei, pk, chunkstart, csr);

    // conv1 (3 grps fused into one dispatch)
    k_gemm<<<gN, B, 0, stream>>>(x, Wb1, Wc1, bc1, dis, bsh, wcomb, NN);
    k_agg<0><<<gN64, B, 0, stream>>>(csr, sd, bsh, dis, wcomb, b1, h,
                                     Wcls, bcls, p, NN);

    // conv2 (+ fused edge-cls projection)
    k_gemm<<<gN, B, 0, stream>>>(h, Wb2, Wc2, bc2, dis, bsh, wcomb, NN);
    k_agg<1><<<gN64, B, 0, stream>>>(csr, sd, bsh, dis, wcomb, b2, h,
                                     Wcls, bcls, p, NN);

    // edge output
    k_edge<<<NB_E2, B, 0, stream>>>(ei, p, out);
}

// Round 13
// 329.284 us; speedup vs baseline: 1.1141x; 1.0175x over previous
//
#include <hip/hip_runtime.h>
#include <hip/hip_fp16.h>

#define NN 50000
#define NNP 50048        // padded node count for table rows
#define EE 800000
#define CH 32            // count chunks (25000 edges each)
#define CHE (EE / CH)    // 25000
#define NB_E2 1563       // ceil(400000/256): 2 edges/thread grids (k_edge)
#define NWIN 4           // windows (XCD pairs): csr seg ~800KB fits per-XCD L2
#define WIN 12500        // node-window per slot (4 * 12500 = 50000)
#define EPB 1024         // edges per fill chunk (256 thr x 4)
#define NCHUNK 782       // ceil(800000/1024)

// ---------------- windowed LDS count: NO device atomics ----------------
__global__ __launch_bounds__(256) void k_count(
    const int* __restrict__ ei, unsigned* __restrict__ pk, int* __restrict__ part)
{
    __shared__ int hist[WIN];   // 50KB
    int c = blockIdx.x >> 2;
    int w = blockIdx.x & 3;
    int tid = threadIdx.x;
    for (int i = tid; i < WIN; i += 256) hist[i] = 0;
    __syncthreads();
    int e0 = c * CHE;
    unsigned lo = w * WIN;
    const int* cols = ei + EE + e0;
    for (int i = tid; i < CHE / 4; i += 256) {
        int4 cc = *(const int4*)(cols + i * 4);
        unsigned d;
        d = (unsigned)cc.x - lo;
        if (d < WIN) {
            int r = atomicAdd(&hist[d], 1);
            pk[e0 + i * 4 + 0] = (unsigned)cc.x | ((unsigned)c << 16) | ((unsigned)r << 21);
        }
        d = (unsigned)cc.y - lo;
        if (d < WIN) {
            int r = atomicAdd(&hist[d], 1);
            pk[e0 + i * 4 + 1] = (unsigned)cc.y | ((unsigned)c << 16) | ((unsigned)r << 21);
        }
        d = (unsigned)cc.z - lo;
        if (d < WIN) {
            int r = atomicAdd(&hist[d], 1);
            pk[e0 + i * 4 + 2] = (unsigned)cc.z | ((unsigned)c << 16) | ((unsigned)r << 21);
        }
        d = (unsigned)cc.w - lo;
        if (d < WIN) {
            int r = atomicAdd(&hist[d], 1);
            pk[e0 + i * 4 + 3] = (unsigned)cc.w | ((unsigned)c << 16) | ((unsigned)r << 21);
        }
    }
    __syncthreads();
    int* pc = part + (size_t)c * NNP + lo;
    for (int i = tid; i < WIN; i += 256) pc[i] = hist[i];
}

// ---------------- reduce partials -> cnt + dis ----------------
__global__ void k_reduce(const int* __restrict__ part, int* __restrict__ cnt,
                         float* __restrict__ dis) {
    int i = blockIdx.x * 256 + threadIdx.x;
    if (i >= NN) return;
    int v = 0;
#pragma unroll
    for (int c = 0; c < CH; c++) v += part[(size_t)c * NNP + i];
    cnt[i] = v;
    dis[i] = rsqrtf((float)v + 1.0f);  // +1 self loop
}

// ---------------- scan: starts + sd + per-chunk base table ----------------
__global__ void k_scan(const int* __restrict__ cnt, const int* __restrict__ part,
                       int2* __restrict__ sd, int* __restrict__ chunkstart, int n) {
    __shared__ int s[256];
    int tid = threadIdx.x, b = blockIdx.x;
    int i = b * 256 + tid;
    int v = (i < n) ? cnt[i] : 0;
    s[tid] = v;
    __syncthreads();
    for (int off = 1; off < 256; off <<= 1) {
        int t2 = (tid >= off) ? s[tid - off] : 0;
        __syncthreads();
        if (tid >= off) s[tid] += t2;
        __syncthreads();
    }
    int loc = s[tid] - v;   // block-local exclusive
    int lim = b * 256;
    int pre = 0;
    for (int j = tid * 4; j < lim; j += 1024) {
        int4 c4 = *(const int4*)(cnt + j);
        pre += c4.x + c4.y + c4.z + c4.w;
    }
    __syncthreads();
    s[tid] = pre;
    __syncthreads();
    for (int off = 128; off; off >>= 1) {
        if (tid < off) s[tid] += s[tid + off];
        __syncthreads();
    }
    int boff = s[0];
    if (i < n) {
        int st = loc + boff;
        sd[i] = make_int2(st, v);
        int cs = st;
#pragma unroll
        for (int c = 0; c < CH; c++) {
            chunkstart[(size_t)c * NNP + i] = cs;
            cs += part[(size_t)c * NNP + i];
        }
    }
}

// ---------------- CSR fill: atomic-free, windowed scatter, packed reads ----------------
__global__ __launch_bounds__(256) void k_fill(
    const int* __restrict__ ei, const unsigned* __restrict__ pk,
    const int* __restrict__ chunkstart, int* __restrict__ csr)
{
    int w = blockIdx.x & (NWIN - 1);
    int chunk = blockIdx.x >> 2;
    int base = chunk * EPB + threadIdx.x * 4;
    unsigned lo = w * WIN;
    if (base + 3 < EE) {
        int4 rr = *(const int4*)(ei + base);
        uint4 pp = *(const uint4*)(pk + base);
        unsigned c0 = pp.x & 0xffffu, c1 = pp.y & 0xffffu;
        unsigned c2 = pp.z & 0xffffu, c3 = pp.w & 0xffffu;
        if (c0 - lo < WIN) csr[chunkstart[(size_t)((pp.x >> 16) & 31u) * NNP + c0] + (pp.x >> 21)] = rr.x;
        if (c1 - lo < WIN) csr[chunkstart[(size_t)((pp.y >> 16) & 31u) * NNP + c1] + (pp.y >> 21)] = rr.y;
        if (c2 - lo < WIN) csr[chunkstart[(size_t)((pp.z >> 16) & 31u) * NNP + c2] + (pp.z >> 21)] = rr.z;
        if (c3 - lo < WIN) csr[chunkstart[(size_t)((pp.w >> 16) & 31u) * NNP + c3] + (pp.w >> 21)] = rr.w;
    } else {
        for (int e = 0; e < 4; e++) {
            int t = base + e;
            if (t < EE) {
                unsigned pv = pk[t];
                unsigned cgl = pv & 0xffffu;
                if (cgl - lo < WIN)
                    csr[chunkstart[(size_t)((pv >> 16) & 31u) * NNP + cgl] + (pv >> 21)] = ei[t];
            }
        }
    }
}

#define GLOAD_LDS16(g, l) __builtin_amdgcn_global_load_lds( \
    (const __attribute__((address_space(1))) void*)(g),     \
    (__attribute__((address_space(3))) void*)(l), 16, 0, 0)

// ---------------- GEMM: async global_load_lds double-buffer (true T3 pipeline) ----------------
// r8-r12 lesson: x-streaming never overlapped compute — register prefetch gets
// compiler-sunk (r8, VGPR=52), no-LDS thrashes L1 (r9), small tiles lose L2 reuse
// (r10/r11), fused-grp under-fills the chip (r12). global_load_lds is a store-like
// intrinsic hipcc cannot sink past the FMA block: issue stage s+1 into buf[(s+1)&1],
// compute buf[s&1] (loads fly under 2048cy FMA), __syncthreads (drain ~free: loads
// had the whole FMA block to land). LDS written linearly (lane x 16B), so the old
// transpose becomes: SOURCE-swizzled storage + XOR-swizzled ds_read_b128
// (slot = tid*8 + (j ^ (tid&7)) -> 8 lanes per 16B column, conflict-free).
// Logical k order per output unchanged -> bit-identical FMA order vs r8.
__global__ __launch_bounds__(256) void k_gemm(
    const float* __restrict__ x, const float* __restrict__ Wb,
    const float* __restrict__ Wc, const float* __restrict__ bc,
    const float* __restrict__ dis,
    __half* __restrict__ bsh, float* __restrict__ wcomb, int n)
{
    __shared__ float buf[2][256 * 32];   // 2 x 32KB; slot sidx holds 16B
    int tid = threadIdx.x;
    int grp = blockIdx.y;
    int row0 = blockIdx.x * 256;
    int row = row0 + tid;
    bool valid = row < n;
    float d = valid ? dis[row] : 0.f;    // issued first: oldest vmem op

    const float* W = (grp < 2) ? (Wb + grp * 32) : Wc;
    const int ldw = (grp < 2) ? 64 : 32;

    float acc[32];
#pragma unroll
    for (int c = 0; c < 32; c++) acc[c] = 0.f;

    // issue one stage's loads: slot sidx = i*256+tid; content (r = sidx>>3,
    // k4 = (sidx&7) ^ (r&7)); LDS dest = wave-uniform base + lane*16 (hardware)
    auto issue = [&](int b, int s) {
#pragma unroll
        for (int i = 0; i < 8; i++) {
            int sidx = i * 256 + tid;
            int r = sidx >> 3;
            int k4 = (sidx & 7) ^ (r & 7);
            int gr = row0 + r;
            if (gr >= n) gr = n - 1;     // clamp: in-bounds garbage, rows unused
            const float* src = x + (size_t)gr * 128 + s * 32 + k4 * 4;
            float* dst = &buf[b][(size_t)(i * 256 + (tid & ~63)) * 4];
            GLOAD_LDS16(src, dst);
        }
    };

    issue(0, 0);
    __syncthreads();                     // drain stage 0 (once)

    for (int s = 0; s < 4; s++) {
        if (s < 3) issue((s + 1) & 1, s + 1);   // fly under the FMA block
        const float* Ws = W + s * 32 * ldw;
        const float* bp = buf[s & 1];
#pragma unroll
        for (int j = 0; j < 8; j++) {
            int slot = tid * 8 + (j ^ (tid & 7));
            float4 v = *(const float4*)(bp + (size_t)slot * 4);
            const float* wk0 = Ws + (j * 4 + 0) * ldw;
            const float* wk1 = Ws + (j * 4 + 1) * ldw;
            const float* wk2 = Ws + (j * 4 + 2) * ldw;
            const float* wk3 = Ws + (j * 4 + 3) * ldw;
#pragma unroll
            for (int c = 0; c < 32; c++) acc[c] = fmaf(v.x, wk0[c], acc[c]);
#pragma unroll
            for (int c = 0; c < 32; c++) acc[c] = fmaf(v.y, wk1[c], acc[c]);
#pragma unroll
            for (int c = 0; c < 32; c++) acc[c] = fmaf(v.z, wk2[c], acc[c]);
#pragma unroll
            for (int c = 0; c < 32; c++) acc[c] = fmaf(v.w, wk3[c], acc[c]);
        }
        __syncthreads();                 // buffer-reuse fence; loads already landed
    }

    if (!valid) return;
    if (grp < 2) {
        __half2 hh[16];
#pragma unroll
        for (int c = 0; c < 16; c++)
            hh[c] = __floats2half2_rn(acc[2 * c] * d, acc[2 * c + 1] * d);
        uint4* bo = (uint4*)(bsh + (size_t)row * 64 + grp * 32);
        const uint4* src = (const uint4*)hh;
#pragma unroll
        for (int c = 0; c < 4; c++) bo[c] = src[c];
    } else {
        float4* wo = (float4*)(wcomb + (size_t)row * 32);
#pragma unroll
        for (int c = 0; c < 8; c++)
            wo[c] = make_float4(acc[4*c] + bc[4*c], acc[4*c+1] + bc[4*c+1],
                                acc[4*c+2] + bc[4*c+2], acc[4*c+3] + bc[4*c+3]);
    }
}

// ---------------- fused aggregate (fp16 gather, pipelined, 8 edges/iter) + combine ----------------
template<int LAYER2>
__global__ __launch_bounds__(256) void k_agg(
    const int* __restrict__ csr, const int2* __restrict__ sd,
    const __half* __restrict__ bsh, const float* __restrict__ dis,
    const float* __restrict__ wcomb, const float* __restrict__ bias,
    float* __restrict__ h,
    const float* __restrict__ Wcls, const float* __restrict__ bcls,
    float* __restrict__ p, int n)
{
    int wid = (blockIdx.x * 256 + threadIdx.x) >> 6;
    int lane = threadIdx.x & 63;
    if (wid >= n) return;
    int2 s2 = sd[wid];
    int start = s2.x, deg = s2.y;
    int g = lane >> 4, q = lane & 15;

    const uint2* bsp = (const uint2*)bsh;
    float4 acc4 = make_float4(0.f, 0.f, 0.f, 0.f);
    if (g == 0) {  // self-loop term (pre-scaled)
        uint2 v = bsp[(size_t)wid * 16 + q];
        float2 lo = __half22float2(*(const __half2*)&v.x);
        float2 hi = __half22float2(*(const __half2*)&v.y);
        acc4 = make_float4(lo.x, lo.y, hi.x, hi.y);
    }

    int j = 0;
    int ia = 0, ib = 0;
    if (8 <= deg) { ia = csr[start + g]; ib = csr[start + 4 + g]; }
    while (j + 8 <= deg) {
        int jn = j + 8;
        int na = 0, nb = 0;
        if (jn + 8 <= deg) { na = csr[start + jn + g]; nb = csr[start + jn + 4 + g]; }
        uint2 v0 = bsp[(size_t)ia * 16 + q];
        uint2 v1 = bsp[(size_t)ib * 16 + q];
        float2 l0 = __half22float2(*(const __half2*)&v0.x);
        float2 h0 = __half22float2(*(const __half2*)&v0.y);
        float2 l1 = __half22float2(*(const __half2*)&v1.x);
        float2 h1 = __half22float2(*(const __half2*)&v1.y);
        acc4.x += l0.x + l1.x;
        acc4.y += l0.y + l1.y;
        acc4.z += h0.x + h1.x;
        acc4.w += h0.y + h1.y;
        ia = na; ib = nb; j = jn;
    }
    int last = start + deg - 1;
    for (; j < deg; j += 4) {
        int idx = start + j + g;
        int r = csr[min(idx, last)];
        uint2 v = bsp[(size_t)r * 16 + q];
        float2 lo = __half22float2(*(const __half2*)&v.x);
        float2 hi = __half22float2(*(const __half2*)&v.y);
        float m = (j + g < deg) ? 1.f : 0.f;
        acc4.x = fmaf(lo.x, m, acc4.x);
        acc4.y = fmaf(lo.y, m, acc4.y);
        acc4.z = fmaf(hi.x, m, acc4.z);
        acc4.w = fmaf(hi.y, m, acc4.w);
    }

    acc4.x += __shfl_xor(acc4.x, 16, 64);
    acc4.y += __shfl_xor(acc4.y, 16, 64);
    acc4.z += __shfl_xor(acc4.z, 16, 64);
    acc4.w += __shfl_xor(acc4.w, 16, 64);
    acc4.x += __shfl_xor(acc4.x, 32, 64);
    acc4.y += __shfl_xor(acc4.y, 32, 64);
    acc4.z += __shfl_xor(acc4.z, 32, 64);
    acc4.w += __shfl_xor(acc4.w, 32, 64);

    float d = dis[wid];
    acc4.x *= d; acc4.y *= d; acc4.z *= d; acc4.w *= d;

    int src = lane >> 2;
    float t0 = __shfl(acc4.x, src, 64);
    float t1 = __shfl(acc4.y, src, 64);
    float t2 = __shfl(acc4.z, src, 64);
    float t3 = __shfl(acc4.w, src, 64);
    int c = lane & 3;
    float acc = (c == 0) ? t0 : (c == 1) ? t1 : (c == 2) ? t2 : t3;

    int fh = lane & 15;
    float a0 = __shfl(acc, fh, 64);
    float a1 = __shfl(acc, 16 + fh, 64);
    float a2 = __shfl(acc, 32 + fh, 64);
    float a3 = __shfl(acc, 48 + fh, 64);
    const float* wn = wcomb + (size_t)wid * 32;
    int hd = lane >> 4;
    float s1 = bias[lane];
    float s2v = bias[64 + lane];
    s1 = fmaf(wn[hd * 4 + 0], a0, s1);
    s1 = fmaf(wn[hd * 4 + 1], a1, s1);
    s1 = fmaf(wn[hd * 4 + 2], a2, s1);
    s1 = fmaf(wn[hd * 4 + 3], a3, s1);
    s2v = fmaf(wn[(4 + hd) * 4 + 0], a0, s2v);
    s2v = fmaf(wn[(4 + hd) * 4 + 1], a1, s2v);
    s2v = fmaf(wn[(4 + hd) * 4 + 2], a2, s2v);
    s2v = fmaf(wn[(4 + hd) * 4 + 3], a3, s2v);

    if (!LAYER2) {
        s1 = fmaxf(s1, 0.f);
        s2v = fmaxf(s2v, 0.f);
        h[(size_t)wid * 128 + lane] = s1;
        h[(size_t)wid * 128 + 64 + lane] = s2v;
    } else {
        float r0 = s1 * Wcls[lane * 2 + 0] + s2v * Wcls[(64 + lane) * 2 + 0];
        float r1 = s1 * Wcls[lane * 2 + 1] + s2v * Wcls[(64 + lane) * 2 + 1];
        float r2 = s1 * Wcls[(128 + lane) * 2 + 0] + s2v * Wcls[(192 + lane) * 2 + 0];
        float r3 = s1 * Wcls[(128 + lane) * 2 + 1] + s2v * Wcls[(192 + lane) * 2 + 1];
#pragma unroll
        for (int off = 32; off; off >>= 1) {
            r0 += __shfl_xor(r0, off, 64);
            r1 += __shfl_xor(r1, off, 64);
            r2 += __shfl_xor(r2, off, 64);
            r3 += __shfl_xor(r3, off, 64);
        }
        if (lane == 0) {
            p[wid * 4 + 0] = r0 + bcls[0];
            p[wid * 4 + 1] = r1 + bcls[1];
            p[wid * 4 + 2] = r2;
            p[wid * 4 + 3] = r3;
        }
    }
}

// ---------------- edge output: 2 edges/thread ----------------
__global__ void k_edge(const int* __restrict__ ei, const float* __restrict__ p,
                       float* __restrict__ out)
{
    int t = blockIdx.x * blockDim.x + threadIdx.x;
    if (t >= EE / 2) return;
    int2 rr = *(const int2*)(ei + 2 * t);
    int2 cc = *(const int2*)(ei + EE + 2 * t);
    float2 pt0 = *(const float2*)(p + rr.x * 4);
    float2 pt1 = *(const float2*)(p + rr.y * 4);
    float2 pb0 = *(const float2*)(p + cc.x * 4 + 2);
    float2 pb1 = *(const float2*)(p + cc.y * 4 + 2);
    float4 o;
    o.x = pt0.x + pb0.x;
    o.y = pt0.y + pb0.y;
    o.z = pt1.x + pb1.x;
    o.w = pt1.y + pb1.y;
    *(float4*)(out + (size_t)t * 4) = o;
}

extern "C" void kernel_launch(void* const* d_in, const int* in_sizes, int n_in,
                              void* d_out, int out_size, void* d_ws, size_t ws_size,
                              hipStream_t stream) {
    const float* x    = (const float*)d_in[0];
    const int*   ei   = (const int*)d_in[1];
    const float* Wb1  = (const float*)d_in[2];
    const float* Wc1  = (const float*)d_in[3];
    const float* bc1  = (const float*)d_in[4];
    const float* b1   = (const float*)d_in[5];
    const float* Wb2  = (const float*)d_in[6];
    const float* Wc2  = (const float*)d_in[7];
    const float* bc2  = (const float*)d_in[8];
    const float* b2   = (const float*)d_in[9];
    const float* Wcls = (const float*)d_in[10];
    const float* bcls = (const float*)d_in[11];
    float* out = (float*)d_out;

    char* ws = (char*)d_ws;
    size_t off = 0;
    auto alloc = [&](size_t bytes) {
        void* pp = ws + off;
        off += (bytes + 15) & ~(size_t)15;
        return pp;
    };

    float*    dis    = (float*)alloc(50048 * 4);
    __half*   bsh    = (__half*)alloc((size_t)NN * 64 * 2);
    float*    wcomb  = (float*)alloc((size_t)NN * 32 * 4);
    float*    h      = (float*)alloc((size_t)NN * 128 * 4);
    float*    p      = (float*)alloc((size_t)NN * 4 * 4);
    int*      cnt    = (int*)alloc(50048 * 4);
    int2*     sd     = (int2*)alloc((size_t)50048 * 8);
    int*      csr    = (int*)alloc((size_t)EE * 4);
    unsigned* pk     = (unsigned*)alloc((size_t)EE * 4);
    int*      part   = (int*)alloc((size_t)CH * NNP * 4);       // 6.4 MB
    int*      chunkstart = (int*)alloc((size_t)CH * NNP * 4);   // 6.4 MB

    const int B = 256;
    int gN   = (NN + B - 1) / B;   // 196
    int gN64 = (NN * 64) / B;      // 12500
    dim3 gG(gN, 3);

    // CSR build (shared by both layers) — no memset, no device atomics
    k_count<<<CH * NWIN, B, 0, stream>>>(ei, pk, part);
    k_reduce<<<gN, B, 0, stream>>>(part, cnt, dis);
    k_scan<<<gN, B, 0, stream>>>(cnt, part, sd, chunkstart, NN);
    k_fill<<<NCHUNK * NWIN, B, 0, stream>>>(ei, pk, chunkstart, csr);

    // conv1
    k_gemm<<<gG, B, 0, stream>>>(x, Wb1, Wc1, bc1, dis, bsh, wcomb, NN);
    k_agg<0><<<gN64, B, 0, stream>>>(csr, sd, bsh, dis, wcomb, b1, h,
                                     Wcls, bcls, p, NN);

    // conv2 (+ fused edge-cls projection)
    k_gemm<<<gG, B, 0, stream>>>(h, Wb2, Wc2, bc2, dis, bsh, wcomb, NN);
    k_agg<1><<<gN64, B, 0, stream>>>(csr, sd, bsh, dis, wcomb, b2, h,
                                     Wcls, bcls, p, NN);

    // edge output
    k_edge<<<NB_E2, B, 0, stream>>>(ei, p, out);
}

// Round 14
// 259.300 us; speedup vs baseline: 1.4148x; 1.2699x over previous
//
#include <hip/hip_runtime.h>
#include <hip/hip_fp16.h>

#define NN 50000
#define NNP 50048        // padded node count for table rows
#define EE 800000
#define CH 32            // count chunks (25000 edges each)
#define CHE (EE / CH)    // 25000
#define NB_E2 1563       // ceil(400000/256): 2 edges/thread grids (k_edge)
#define NWIN 4           // windows (XCD pairs): csr seg ~800KB fits per-XCD L2
#define WIN 12500        // node-window per slot (4 * 12500 = 50000)
#define EPB 1024         // edges per fill chunk (256 thr x 4)
#define NCHUNK 782       // ceil(800000/1024)

// ---------------- windowed LDS count: NO device atomics ----------------
__global__ __launch_bounds__(256) void k_count(
    const int* __restrict__ ei, unsigned* __restrict__ pk, int* __restrict__ part)
{
    __shared__ int hist[WIN];   // 50KB
    int c = blockIdx.x >> 2;
    int w = blockIdx.x & 3;
    int tid = threadIdx.x;
    for (int i = tid; i < WIN; i += 256) hist[i] = 0;
    __syncthreads();
    int e0 = c * CHE;
    unsigned lo = w * WIN;
    const int* cols = ei + EE + e0;
    for (int i = tid; i < CHE / 4; i += 256) {
        int4 cc = *(const int4*)(cols + i * 4);
        unsigned d;
        d = (unsigned)cc.x - lo;
        if (d < WIN) {
            int r = atomicAdd(&hist[d], 1);
            pk[e0 + i * 4 + 0] = (unsigned)cc.x | ((unsigned)c << 16) | ((unsigned)r << 21);
        }
        d = (unsigned)cc.y - lo;
        if (d < WIN) {
            int r = atomicAdd(&hist[d], 1);
            pk[e0 + i * 4 + 1] = (unsigned)cc.y | ((unsigned)c << 16) | ((unsigned)r << 21);
        }
        d = (unsigned)cc.z - lo;
        if (d < WIN) {
            int r = atomicAdd(&hist[d], 1);
            pk[e0 + i * 4 + 2] = (unsigned)cc.z | ((unsigned)c << 16) | ((unsigned)r << 21);
        }
        d = (unsigned)cc.w - lo;
        if (d < WIN) {
            int r = atomicAdd(&hist[d], 1);
            pk[e0 + i * 4 + 3] = (unsigned)cc.w | ((unsigned)c << 16) | ((unsigned)r << 21);
        }
    }
    __syncthreads();
    int* pc = part + (size_t)c * NNP + lo;
    for (int i = tid; i < WIN; i += 256) pc[i] = hist[i];
}

// ---------------- reduce partials -> cnt + dis ----------------
__global__ void k_reduce(const int* __restrict__ part, int* __restrict__ cnt,
                         float* __restrict__ dis) {
    int i = blockIdx.x * 256 + threadIdx.x;
    if (i >= NN) return;
    int v = 0;
#pragma unroll
    for (int c = 0; c < CH; c++) v += part[(size_t)c * NNP + i];
    cnt[i] = v;
    dis[i] = rsqrtf((float)v + 1.0f);  // +1 self loop
}

// ---------------- scan: starts + sd + per-chunk base table ----------------
__global__ void k_scan(const int* __restrict__ cnt, const int* __restrict__ part,
                       int2* __restrict__ sd, int* __restrict__ chunkstart, int n) {
    __shared__ int s[256];
    int tid = threadIdx.x, b = blockIdx.x;
    int i = b * 256 + tid;
    int v = (i < n) ? cnt[i] : 0;
    s[tid] = v;
    __syncthreads();
    for (int off = 1; off < 256; off <<= 1) {
        int t2 = (tid >= off) ? s[tid - off] : 0;
        __syncthreads();
        if (tid >= off) s[tid] += t2;
        __syncthreads();
    }
    int loc = s[tid] - v;   // block-local exclusive
    int lim = b * 256;
    int pre = 0;
    for (int j = tid * 4; j < lim; j += 1024) {
        int4 c4 = *(const int4*)(cnt + j);
        pre += c4.x + c4.y + c4.z + c4.w;
    }
    __syncthreads();
    s[tid] = pre;
    __syncthreads();
    for (int off = 128; off; off >>= 1) {
        if (tid < off) s[tid] += s[tid + off];
        __syncthreads();
    }
    int boff = s[0];
    if (i < n) {
        int st = loc + boff;
        sd[i] = make_int2(st, v);
        int cs = st;
#pragma unroll
        for (int c = 0; c < CH; c++) {
            chunkstart[(size_t)c * NNP + i] = cs;
            cs += part[(size_t)c * NNP + i];
        }
    }
}

// ---------------- CSR fill: atomic-free, windowed scatter, packed reads ----------------
__global__ __launch_bounds__(256) void k_fill(
    const int* __restrict__ ei, const unsigned* __restrict__ pk,
    const int* __restrict__ chunkstart, int* __restrict__ csr)
{
    int w = blockIdx.x & (NWIN - 1);
    int chunk = blockIdx.x >> 2;
    int base = chunk * EPB + threadIdx.x * 4;
    unsigned lo = w * WIN;
    if (base + 3 < EE) {
        int4 rr = *(const int4*)(ei + base);
        uint4 pp = *(const uint4*)(pk + base);
        unsigned c0 = pp.x & 0xffffu, c1 = pp.y & 0xffffu;
        unsigned c2 = pp.z & 0xffffu, c3 = pp.w & 0xffffu;
        if (c0 - lo < WIN) csr[chunkstart[(size_t)((pp.x >> 16) & 31u) * NNP + c0] + (pp.x >> 21)] = rr.x;
        if (c1 - lo < WIN) csr[chunkstart[(size_t)((pp.y >> 16) & 31u) * NNP + c1] + (pp.y >> 21)] = rr.y;
        if (c2 - lo < WIN) csr[chunkstart[(size_t)((pp.z >> 16) & 31u) * NNP + c2] + (pp.z >> 21)] = rr.z;
        if (c3 - lo < WIN) csr[chunkstart[(size_t)((pp.w >> 16) & 31u) * NNP + c3] + (pp.w >> 21)] = rr.w;
    } else {
        for (int e = 0; e < 4; e++) {
            int t = base + e;
            if (t < EE) {
                unsigned pv = pk[t];
                unsigned cgl = pv & 0xffffu;
                if (cgl - lo < WIN)
                    csr[chunkstart[(size_t)((pv >> 16) & 31u) * NNP + cgl] + (pv >> 21)] = ei[t];
            }
        }
    }
}

// ---------------- GEMM: LDS-staged x, thread-per-row (r8 best: 47us/dispatch) ----------------
// r9-r13 established this is the plateau: no-LDS thrashes L1, smaller tiles lose
// L2 reuse, fused-grp under-fills grid, async-dbuf halves occupancy via LDS.
__global__ __launch_bounds__(256) void k_gemm(
    const float* __restrict__ x, const float* __restrict__ Wb,
    const float* __restrict__ Wc, const float* __restrict__ bc,
    const float* __restrict__ dis,
    __half* __restrict__ bsh, float* __restrict__ wcomb, int n)
{
    __shared__ float xt[32 * 257];  // transposed tile: xt[k][row]
    int tid = threadIdx.x;
    int grp = blockIdx.y;
    int row0 = blockIdx.x * 256;
    int row = row0 + tid;
    bool valid = row < n;

    const float* W = (grp < 2) ? (Wb + grp * 32) : Wc;
    const int ldw = (grp < 2) ? 64 : 32;

    float acc[32];
#pragma unroll
    for (int c = 0; c < 32; c++) acc[c] = 0.f;

    float4 v[8];
#pragma unroll
    for (int i = 0; i < 8; i++) {
        int idx = i * 256 + tid;
        int r = idx >> 3;
        int k4 = idx & 7;
        int gr = row0 + r;
        v[i] = (gr < n) ? *(const float4*)(x + (size_t)gr * 128 + k4 * 4)
                        : make_float4(0.f, 0.f, 0.f, 0.f);
    }

    for (int s = 0; s < 4; s++) {
        __syncthreads();
#pragma unroll
        for (int i = 0; i < 8; i++) {
            int idx = i * 256 + tid;
            int r = idx >> 3;
            int k4 = idx & 7;
            xt[(k4 * 4 + 0) * 257 + r] = v[i].x;
            xt[(k4 * 4 + 1) * 257 + r] = v[i].y;
            xt[(k4 * 4 + 2) * 257 + r] = v[i].z;
            xt[(k4 * 4 + 3) * 257 + r] = v[i].w;
        }
        __syncthreads();

        if (s < 3) {
            int base_k = (s + 1) * 32;
#pragma unroll
            for (int i = 0; i < 8; i++) {
                int idx = i * 256 + tid;
                int r = idx >> 3;
                int k4 = idx & 7;
                int gr = row0 + r;
                v[i] = (gr < n) ? *(const float4*)(x + (size_t)gr * 128 + base_k + k4 * 4)
                                : make_float4(0.f, 0.f, 0.f, 0.f);
            }
        }

        const float* Ws = W + s * 32 * ldw;
#pragma unroll 8
        for (int k = 0; k < 32; k++) {
            float xs = xt[k * 257 + tid];
            const float* wk = Ws + k * ldw;
#pragma unroll
            for (int c = 0; c < 32; c++) acc[c] = fmaf(xs, wk[c], acc[c]);
        }
    }

    if (!valid) return;
    if (grp < 2) {
        float d = dis[row];
        __half2 hh[16];
#pragma unroll
        for (int c = 0; c < 16; c++)
            hh[c] = __floats2half2_rn(acc[2 * c] * d, acc[2 * c + 1] * d);
        uint4* bo = (uint4*)(bsh + (size_t)row * 64 + grp * 32);
        const uint4* src = (const uint4*)hh;
#pragma unroll
        for (int c = 0; c < 4; c++) bo[c] = src[c];
    } else {
        float4* wo = (float4*)(wcomb + (size_t)row * 32);
#pragma unroll
        for (int c = 0; c < 8; c++)
            wo[c] = make_float4(acc[4*c] + bc[4*c], acc[4*c+1] + bc[4*c+1],
                                acc[4*c+2] + bc[4*c+2], acc[4*c+3] + bc[4*c+3]);
    }
}

// ---------------- fused aggregate: 16 edges/iter (4-deep gather MLP) + combine ----------------
// agg theory (r13): ~46us/layer vs ~12us memory floor -> per-wave latency-bound
// on serial rounds of random 128B bsh gathers (6.4MB table thrashes 4MB XCD L2).
// Main loop now keeps 4 gather instrs (16 edges) in flight (was 2/8); tail is
// 8-wide masked (was 4-wide): typical serial rounds ~4 -> ~2 per wave.
template<int LAYER2>
__global__ __launch_bounds__(256) void k_agg(
    const int* __restrict__ csr, const int2* __restrict__ sd,
    const __half* __restrict__ bsh, const float* __restrict__ dis,
    const float* __restrict__ wcomb, const float* __restrict__ bias,
    float* __restrict__ h,
    const float* __restrict__ Wcls, const float* __restrict__ bcls,
    float* __restrict__ p, int n)
{
    int wid = (blockIdx.x * 256 + threadIdx.x) >> 6;
    int lane = threadIdx.x & 63;
    if (wid >= n) return;
    int2 s2 = sd[wid];
    int start = s2.x, deg = s2.y;
    int g = lane >> 4, q = lane & 15;

    const uint2* bsp = (const uint2*)bsh;
    float4 acc4 = make_float4(0.f, 0.f, 0.f, 0.f);
    if (g == 0) {  // self-loop term (pre-scaled)
        uint2 v = bsp[(size_t)wid * 16 + q];
        float2 lo = __half22float2(*(const __half2*)&v.x);
        float2 hi = __half22float2(*(const __half2*)&v.y);
        acc4 = make_float4(lo.x, lo.y, hi.x, hi.y);
    }

    int j = 0;
    int i0 = 0, i1 = 0, i2 = 0, i3 = 0;
    if (16 <= deg) {
        i0 = csr[start + g];
        i1 = csr[start + 4 + g];
        i2 = csr[start + 8 + g];
        i3 = csr[start + 12 + g];
    }
    while (j + 16 <= deg) {
        int jn = j + 16;
        int n0 = 0, n1 = 0, n2 = 0, n3 = 0;
        if (jn + 16 <= deg) {
            n0 = csr[start + jn + g];
            n1 = csr[start + jn + 4 + g];
            n2 = csr[start + jn + 8 + g];
            n3 = csr[start + jn + 12 + g];
        }
        uint2 v0 = bsp[(size_t)i0 * 16 + q];
        uint2 v1 = bsp[(size_t)i1 * 16 + q];
        uint2 v2 = bsp[(size_t)i2 * 16 + q];
        uint2 v3 = bsp[(size_t)i3 * 16 + q];
        float2 l0 = __half22float2(*(const __half2*)&v0.x);
        float2 h0 = __half22float2(*(const __half2*)&v0.y);
        float2 l1 = __half22float2(*(const __half2*)&v1.x);
        float2 h1 = __half22float2(*(const __half2*)&v1.y);
        float2 l2 = __half22float2(*(const __half2*)&v2.x);
        float2 h2 = __half22float2(*(const __half2*)&v2.y);
        float2 l3 = __half22float2(*(const __half2*)&v3.x);
        float2 h3 = __half22float2(*(const __half2*)&v3.y);
        acc4.x += (l0.x + l1.x) + (l2.x + l3.x);
        acc4.y += (l0.y + l1.y) + (l2.y + l3.y);
        acc4.z += (h0.x + h1.x) + (h2.x + h3.x);
        acc4.w += (h0.y + h1.y) + (h2.y + h3.y);
        i0 = n0; i1 = n1; i2 = n2; i3 = n3; j = jn;
    }
    int last = start + deg - 1;
    while (j < deg) {   // masked 8-wide tail (2 gathers in flight)
        int idxA = start + j + g;
        int idxB = start + j + 4 + g;
        int rA = csr[min(idxA, last)];
        int rB = csr[min(idxB, last)];
        uint2 vA = bsp[(size_t)rA * 16 + q];
        uint2 vB = bsp[(size_t)rB * 16 + q];
        float mA = (j + g < deg) ? 1.f : 0.f;
        float mB = (j + 4 + g < deg) ? 1.f : 0.f;
        float2 lA = __half22float2(*(const __half2*)&vA.x);
        float2 hA = __half22float2(*(const __half2*)&vA.y);
        float2 lB = __half22float2(*(const __half2*)&vB.x);
        float2 hB = __half22float2(*(const __half2*)&vB.y);
        acc4.x = fmaf(lA.x, mA, acc4.x);
        acc4.y = fmaf(lA.y, mA, acc4.y);
        acc4.z = fmaf(hA.x, mA, acc4.z);
        acc4.w = fmaf(hA.y, mA, acc4.w);
        acc4.x = fmaf(lB.x, mB, acc4.x);
        acc4.y = fmaf(lB.y, mB, acc4.y);
        acc4.z = fmaf(hB.x, mB, acc4.z);
        acc4.w = fmaf(hB.y, mB, acc4.w);
        j += 8;
    }

    acc4.x += __shfl_xor(acc4.x, 16, 64);
    acc4.y += __shfl_xor(acc4.y, 16, 64);
    acc4.z += __shfl_xor(acc4.z, 16, 64);
    acc4.w += __shfl_xor(acc4.w, 16, 64);
    acc4.x += __shfl_xor(acc4.x, 32, 64);
    acc4.y += __shfl_xor(acc4.y, 32, 64);
    acc4.z += __shfl_xor(acc4.z, 32, 64);
    acc4.w += __shfl_xor(acc4.w, 32, 64);

    float d = dis[wid];
    acc4.x *= d; acc4.y *= d; acc4.z *= d; acc4.w *= d;

    int src = lane >> 2;
    float t0 = __shfl(acc4.x, src, 64);
    float t1 = __shfl(acc4.y, src, 64);
    float t2 = __shfl(acc4.z, src, 64);
    float t3 = __shfl(acc4.w, src, 64);
    int c = lane & 3;
    float acc = (c == 0) ? t0 : (c == 1) ? t1 : (c == 2) ? t2 : t3;

    int fh = lane & 15;
    float a0 = __shfl(acc, fh, 64);
    float a1 = __shfl(acc, 16 + fh, 64);
    float a2 = __shfl(acc, 32 + fh, 64);
    float a3 = __shfl(acc, 48 + fh, 64);
    const float* wn = wcomb + (size_t)wid * 32;
    int hd = lane >> 4;
    float s1 = bias[lane];
    float s2v = bias[64 + lane];
    s1 = fmaf(wn[hd * 4 + 0], a0, s1);
    s1 = fmaf(wn[hd * 4 + 1], a1, s1);
    s1 = fmaf(wn[hd * 4 + 2], a2, s1);
    s1 = fmaf(wn[hd * 4 + 3], a3, s1);
    s2v = fmaf(wn[(4 + hd) * 4 + 0], a0, s2v);
    s2v = fmaf(wn[(4 + hd) * 4 + 1], a1, s2v);
    s2v = fmaf(wn[(4 + hd) * 4 + 2], a2, s2v);
    s2v = fmaf(wn[(4 + hd) * 4 + 3], a3, s2v);

    if (!LAYER2) {
        s1 = fmaxf(s1, 0.f);
        s2v = fmaxf(s2v, 0.f);
        h[(size_t)wid * 128 + lane] = s1;
        h[(size_t)wid * 128 + 64 + lane] = s2v;
    } else {
        float r0 = s1 * Wcls[lane * 2 + 0] + s2v * Wcls[(64 + lane) * 2 + 0];
        float r1 = s1 * Wcls[lane * 2 + 1] + s2v * Wcls[(64 + lane) * 2 + 1];
        float r2 = s1 * Wcls[(128 + lane) * 2 + 0] + s2v * Wcls[(192 + lane) * 2 + 0];
        float r3 = s1 * Wcls[(128 + lane) * 2 + 1] + s2v * Wcls[(192 + lane) * 2 + 1];
#pragma unroll
        for (int off = 32; off; off >>= 1) {
            r0 += __shfl_xor(r0, off, 64);
            r1 += __shfl_xor(r1, off, 64);
            r2 += __shfl_xor(r2, off, 64);
            r3 += __shfl_xor(r3, off, 64);
        }
        if (lane == 0) {
            p[wid * 4 + 0] = r0 + bcls[0];
            p[wid * 4 + 1] = r1 + bcls[1];
            p[wid * 4 + 2] = r2;
            p[wid * 4 + 3] = r3;
        }
    }
}

// ---------------- edge output: 2 edges/thread ----------------
__global__ void k_edge(const int* __restrict__ ei, const float* __restrict__ p,
                       float* __restrict__ out)
{
    int t = blockIdx.x * blockDim.x + threadIdx.x;
    if (t >= EE / 2) return;
    int2 rr = *(const int2*)(ei + 2 * t);
    int2 cc = *(const int2*)(ei + EE + 2 * t);
    float2 pt0 = *(const float2*)(p + rr.x * 4);
    float2 pt1 = *(const float2*)(p + rr.y * 4);
    float2 pb0 = *(const float2*)(p + cc.x * 4 + 2);
    float2 pb1 = *(const float2*)(p + cc.y * 4 + 2);
    float4 o;
    o.x = pt0.x + pb0.x;
    o.y = pt0.y + pb0.y;
    o.z = pt1.x + pb1.x;
    o.w = pt1.y + pb1.y;
    *(float4*)(out + (size_t)t * 4) = o;
}

extern "C" void kernel_launch(void* const* d_in, const int* in_sizes, int n_in,
                              void* d_out, int out_size, void* d_ws, size_t ws_size,
                              hipStream_t stream) {
    const float* x    = (const float*)d_in[0];
    const int*   ei   = (const int*)d_in[1];
    const float* Wb1  = (const float*)d_in[2];
    const float* Wc1  = (const float*)d_in[3];
    const float* bc1  = (const float*)d_in[4];
    const float* b1   = (const float*)d_in[5];
    const float* Wb2  = (const float*)d_in[6];
    const float* Wc2  = (const float*)d_in[7];
    const float* bc2  = (const float*)d_in[8];
    const float* b2   = (const float*)d_in[9];
    const float* Wcls = (const float*)d_in[10];
    const float* bcls = (const float*)d_in[11];
    float* out = (float*)d_out;

    char* ws = (char*)d_ws;
    size_t off = 0;
    auto alloc = [&](size_t bytes) {
        void* pp = ws + off;
        off += (bytes + 15) & ~(size_t)15;
        return pp;
    };

    float*    dis    = (float*)alloc(50048 * 4);
    __half*   bsh    = (__half*)alloc((size_t)NN * 64 * 2);
    float*    wcomb  = (float*)alloc((size_t)NN * 32 * 4);
    float*    h      = (float*)alloc((size_t)NN * 128 * 4);
    float*    p      = (float*)alloc((size_t)NN * 4 * 4);
    int*      cnt    = (int*)alloc(50048 * 4);
    int2*     sd     = (int2*)alloc((size_t)50048 * 8);
    int*      csr    = (int*)alloc((size_t)EE * 4);
    unsigned* pk     = (unsigned*)alloc((size_t)EE * 4);
    int*      part   = (int*)alloc((size_t)CH * NNP * 4);       // 6.4 MB
    int*      chunkstart = (int*)alloc((size_t)CH * NNP * 4);   // 6.4 MB

    const int B = 256;
    int gN   = (NN + B - 1) / B;   // 196
    int gN64 = (NN * 64) / B;      // 12500
    dim3 gG(gN, 3);

    // CSR build (shared by both layers) — no memset, no device atomics
    k_count<<<CH * NWIN, B, 0, stream>>>(ei, pk, part);
    k_reduce<<<gN, B, 0, stream>>>(part, cnt, dis);
    k_scan<<<gN, B, 0, stream>>>(cnt, part, sd, chunkstart, NN);
    k_fill<<<NCHUNK * NWIN, B, 0, stream>>>(ei, pk, chunkstart, csr);

    // conv1
    k_gemm<<<gG, B, 0, stream>>>(x, Wb1, Wc1, bc1, dis, bsh, wcomb, NN);
    k_agg<0><<<gN64, B, 0, stream>>>(csr, sd, bsh, dis, wcomb, b1, h,
                                     Wcls, bcls, p, NN);

    // conv2 (+ fused edge-cls projection)
    k_gemm<<<gG, B, 0, stream>>>(h, Wb2, Wc2, bc2, dis, bsh, wcomb, NN);
    k_agg<1><<<gN64, B, 0, stream>>>(csr, sd, bsh, dis, wcomb, b2, h,
                                     Wcls, bcls, p, NN);

    // edge output
    k_edge<<<NB_E2, B, 0, stream>>>(ei, p, out);
}